// Round 4
// baseline (481.549 us; speedup 1.0000x reference)
//
#include <hip/hip_runtime.h>
#include <math.h>

#define N_DIM 1000
#define P_DIM 50000
#define Z_DIM 10
#define L_DIM 5
#define NSTEP 50

// precompute grid
#define NTP 256
#define NBP 196          // ceil(50000/256)
#define NSPLIT 4
#define NCHUNK 250       // N_DIM / NSPLIT

// persistent step kernel: plain launch, 49 blocks x 256 thr x 4 p/thread = 50176 >= P.
// Barrier-free: each WAVE (196 total) publishes its own softmax partial and polls
// all 196 partials itself. No __syncthreads, no LDS in the step loop.
#define NT1 256
#define PPT 4
#define PBLK (NT1 * PPT)     // 1024 p per block
#define NBLK 49
#define NWAVES (NBLK * 4)    // 196
#define SLOT_STRIDE 256      // u64 slots reserved per step (196 used)
#define NEG_BIG (-3.0e38f)
#define SPIN_MAX 32768       // bounded spin: sync failure -> wrong result, not a hang

// ---- workspace layout (floats) ----
constexpr size_t ZP       = (size_t)Z_DIM * P_DIM;            // 500000
constexpr size_t OFF_PART = 0;                                // u64[NSTEP*SLOT_STRIDE]
constexpr size_t PART_F   = (size_t)NSTEP * SLOT_STRIDE * 2;  // in floats (25600)
constexpr size_t OFF_ZTRP = PART_F;                           // [NSPLIT][Z][P] (no atomics)
constexpr size_t OFF_W    = OFF_ZTRP + (size_t)NSPLIT * ZP;   // [Z][P] W0
constexpr size_t OFF_ZZ   = OFF_W + ZP;                       // [Z*Z], reserve 128

// ---- output layout (floats) ----
constexpr size_t OUT_MW = 0;
constexpr size_t OUT_VW = (size_t)L_DIM * Z_DIM * P_DIM;      // 2,500,000
constexpr size_t OUT_AL = OUT_VW + (size_t)L_DIM * Z_DIM;     // 2,500,050

// Fused precompute (one launch, grid y = NSPLIT+1 rows):
//  rows 0..NSPLIT-1 : ZtRp[y][z][p] = chunk-y of mean_z^T @ data (plain stores, no atomics)
//                     + W0[z][p] on row 0
//  row  NSPLIT      : bx < 100      -> zz[bx] = mean_z^T mean_z + N*var_z
//                     bx in [100,196)-> zero the NSTEP*SLOT_STRIDE partial slots
__global__ __launch_bounds__(NTP) void precompute_big(const float* __restrict__ data,
                                                      const float* __restrict__ mean_z,
                                                      const float* __restrict__ var_z,
                                                      const float* __restrict__ mw0,
                                                      const float* __restrict__ al0,
                                                      float* __restrict__ ws) {
    if (blockIdx.y == NSPLIT) {
        int bx = blockIdx.x;
        if (bx < Z_DIM * Z_DIM) {
            float* zz = ws + OFF_ZZ;
            int i = bx / Z_DIM, j = bx % Z_DIM;
            float s = 0.f;
            for (int n = threadIdx.x; n < N_DIM; n += NTP)
                s += mean_z[n * Z_DIM + i] * mean_z[n * Z_DIM + j];
            #pragma unroll
            for (int off = 32; off > 0; off >>= 1) s += __shfl_xor(s, off);
            __shared__ float ls[4];
            if ((threadIdx.x & 63) == 0) ls[threadIdx.x >> 6] = s;
            __syncthreads();
            if (threadIdx.x == 0) {
                float t = ls[0] + ls[1] + ls[2] + ls[3];
                zz[bx] = t + (float)N_DIM * var_z[bx];
            }
        } else {
            // zero partial slots (ws is poisoned 0xAA; poisoned slots look "ready")
            unsigned long long* part = reinterpret_cast<unsigned long long*>(ws + OFF_PART);
            int idx = (bx - Z_DIM * Z_DIM) * NTP + threadIdx.x;
            if (idx < NSTEP * SLOT_STRIDE) part[idx] = 0ULL;
        }
        return;
    }

    float* ZtRp = ws + OFF_ZTRP + (size_t)blockIdx.y * ZP;
    float* W    = ws + OFF_W;
    __shared__ float mzs[NCHUNK * Z_DIM];   // 10 KB
    int n0 = blockIdx.y * NCHUNK;
    for (int i = threadIdx.x; i < NCHUNK * Z_DIM; i += NTP)
        mzs[i] = mean_z[n0 * Z_DIM + i];
    __syncthreads();
    int p = blockIdx.x * NTP + threadIdx.x;
    if (p >= P_DIM) return;

    float acc[Z_DIM];
    #pragma unroll
    for (int z = 0; z < Z_DIM; z++) acc[z] = 0.f;
    for (int r = 0; r < NCHUNK; r++) {
        float d = data[(size_t)(n0 + r) * P_DIM + p];
        #pragma unroll
        for (int z = 0; z < Z_DIM; z++) acc[z] = fmaf(mzs[r * Z_DIM + z], d, acc[z]);
    }
    #pragma unroll
    for (int z = 0; z < Z_DIM; z++) ZtRp[(size_t)z * P_DIM + p] = acc[z];

    if (blockIdx.y == 0) {
        #pragma unroll
        for (int z = 0; z < Z_DIM; z++) {
            float w = 0.f;
            #pragma unroll
            for (int l = 0; l < L_DIM; l++) {
                size_t io = ((size_t)l * Z_DIM + z) * P_DIM + p;
                w = fmaf(mw0[io], al0[io], w);
            }
            W[(size_t)z * P_DIM + p] = w;
        }
    }
}

// All 50 (k,l) steps in one persistent kernel. Per-p state in registers throughout.
// Per step, per wave: butterfly max -> exps -> butterfly sum -> publish packed (Mw,Ew)
// -> prefetch next inputs -> poll 196 slots -> two-pass merge -> finalize. Barrier-free.
__global__ __launch_bounds__(NT1) void steps_fused(const float* __restrict__ mw0,
                                                   const float* __restrict__ al0,
                                                   const float* __restrict__ pi,
                                                   const float* __restrict__ tau0,
                                                   const float* __restrict__ taup,
                                                   float* __restrict__ ws,
                                                   float* __restrict__ out) {
    const float* ZtRp = ws + OFF_ZTRP;
    const float* Wg   = ws + OFF_W;
    const float* zz   = ws + OFF_ZZ;
    unsigned long long* part = reinterpret_cast<unsigned long long*>(ws + OFF_PART);
    float* out_mw = out + OUT_MW;
    float* out_vw = out + OUT_VW;
    float* out_al = out + OUT_AL;

    const int tid  = threadIdx.x;
    const int bid  = blockIdx.x;
    const int lane = tid & 63;
    const int wid  = tid >> 6;
    const int gw   = bid * 4 + wid;              // global wave id, 0..195
    const int p0   = bid * PBLK + tid * PPT;     // 4 consecutive p; P%4==0 -> all-or-none
    const bool valid = p0 < P_DIM;
    const float tau = taup[0];
    const bool need3 = lane < (NWAVES - 192);    // lanes 0..3 own a 4th slot

    // ---- per-p register state (all indices compile-time after unroll) ----
    float W[Z_DIM][PPT];
    #pragma unroll
    for (int z = 0; z < Z_DIM; z++)
        #pragma unroll
        for (int i = 0; i < PPT; i++) W[z][i] = 0.f;
    float mw_c[PPT], al_c[PPT], lpi[PPT], zk[PPT];
    #pragma unroll
    for (int i = 0; i < PPT; i++) { mw_c[i] = 0.f; al_c[i] = 0.f; lpi[i] = 0.f; zk[i] = 0.f; }
    if (valid) {
        #pragma unroll
        for (int z = 0; z < Z_DIM; z++) {
            float4 t = *reinterpret_cast<const float4*>(Wg + (size_t)z * P_DIM + p0);
            W[z][0] = t.x; W[z][1] = t.y; W[z][2] = t.z; W[z][3] = t.w;
        }
        float4 tm = *reinterpret_cast<const float4*>(mw0 + p0);   // step 0: k=0,l=0
        float4 ta = *reinterpret_cast<const float4*>(al0 + p0);
        mw_c[0] = tm.x; mw_c[1] = tm.y; mw_c[2] = tm.z; mw_c[3] = tm.w;
        al_c[0] = ta.x; al_c[1] = ta.y; al_c[2] = ta.z; al_c[3] = ta.w;
        #pragma unroll
        for (int i = 0; i < PPT; i++) lpi[i] = __logf(pi[p0 + i]);
        #pragma unroll
        for (int y = 0; y < NSPLIT; y++) {                        // Zt[k=0], no atomics
            float4 t = *reinterpret_cast<const float4*>(ZtRp + ((size_t)y * Z_DIM + 0) * P_DIM + p0);
            zk[0] += t.x; zk[1] += t.y; zk[2] += t.z; zk[3] += t.w;
        }
    }

    float wk[PPT], r[PPT];
    #pragma unroll
    for (int i = 0; i < PPT; i++) { wk[i] = 0.f; r[i] = 0.f; }
    int k = 0, l = 0;

    #pragma unroll 1
    for (int s = 0; s < NSTEP; s++) {
        // ---- per-step uniform scalars ----
        const float Ezz   = zz[k * Z_DIM + k];
        const float t0v   = tau0[l * Z_DIM + k];
        const float u_var = 1.f / (tau * Ezz + t0v);
        const float s2    = 1.f / (Ezz * tau);
        const float s0inv = 1.f / t0v;
        const float cq    = 0.5f * (tau / Ezz) * (s0inv / (s2 + s0inv));

        if (l == 0) {
            // fresh factor k: r = Zt[k] - sum_{j!=k} zz[k,j]*W[j]; wk = W[k]
            #pragma unroll
            for (int i = 0; i < PPT; i++) r[i] = zk[i];
            #pragma unroll
            for (int j = 0; j < Z_DIM; j++) {
                float c = (j == k) ? 0.f : zz[k * Z_DIM + j];     // uniform select
                #pragma unroll
                for (int i = 0; i < PPT; i++) r[i] = fmaf(-c, W[j][i], r[i]);
                if (j == k)
                    #pragma unroll
                    for (int i = 0; i < PPT; i++) wk[i] = W[j][i];
            }
        }

        // ---- compute step (k,l) logits ----
        const size_t io = ((size_t)l * Z_DIM + k) * P_DIM + p0;
        float wkl[PPT], um[PPT], lgt[PPT];
        #pragma unroll
        for (int i = 0; i < PPT; i++) { wkl[i] = 0.f; um[i] = 0.f; lgt[i] = NEG_BIG; }
        if (valid) {
            #pragma unroll
            for (int i = 0; i < PPT; i++) {
                wkl[i] = wk[i] - mw_c[i] * al_c[i];
                float E = fmaf(-Ezz, wkl[i], r[i]);
                um[i]  = tau * u_var * E;
                lgt[i] = fmaf(cq * E, E, lpi[i]);
            }
            float4 sv = make_float4(um[0], um[1], um[2], um[3]);
            *reinterpret_cast<float4*>(out_mw + io) = sv;
        }

        // ---- wave-level two-pass softmax (no barriers, no LDS) ----
        float m4 = fmaxf(fmaxf(lgt[0], lgt[1]), fmaxf(lgt[2], lgt[3]));
        #pragma unroll
        for (int off = 32; off > 0; off >>= 1) m4 = fmaxf(m4, __shfl_xor(m4, off));
        const float Mw = m4;                       // wave max, all lanes
        float esv[PPT];
        #pragma unroll
        for (int i = 0; i < PPT; i++) esv[i] = __expf(lgt[i] - Mw);  // invalid -> 0
        float s4 = (esv[0] + esv[1]) + (esv[2] + esv[3]);
        #pragma unroll
        for (int off = 32; off > 0; off >>= 1) s4 += __shfl_xor(s4, off);
        if (lane == 0) {
            // pack (Mw, Ew): every wave has >=1 valid lane -> Ew >= 1 -> hi word != 0
            unsigned long long v = ((unsigned long long)__float_as_uint(s4) << 32)
                                 | (unsigned long long)__float_as_uint(Mw);
            __hip_atomic_store(&part[(size_t)s * SLOT_STRIDE + gw], v, __ATOMIC_RELAXED,
                               __HIP_MEMORY_SCOPE_AGENT);
        }

        // ---- prefetch next step's inputs BEFORE the poll (hides L3 latency) ----
        int kn = k, ln = l + 1;
        if (ln == L_DIM) { ln = 0; kn++; }
        float mw_n[PPT], al_n[PPT];
        #pragma unroll
        for (int i = 0; i < PPT; i++) { mw_n[i] = 0.f; al_n[i] = 0.f; }
        if (valid && s + 1 < NSTEP) {
            size_t ion = ((size_t)ln * Z_DIM + kn) * P_DIM + p0;
            float4 tm = *reinterpret_cast<const float4*>(mw0 + ion);
            float4 ta = *reinterpret_cast<const float4*>(al0 + ion);
            mw_n[0] = tm.x; mw_n[1] = tm.y; mw_n[2] = tm.z; mw_n[3] = tm.w;
            al_n[0] = ta.x; al_n[1] = ta.y; al_n[2] = ta.z; al_n[3] = ta.w;
            if (ln == 0) {                        // next factor: lpi + Zt[kn] early
                #pragma unroll
                for (int i = 0; i < PPT; i++) lpi[i] = __logf(pi[(size_t)kn * P_DIM + p0 + i]);
                #pragma unroll
                for (int i = 0; i < PPT; i++) zk[i] = 0.f;
                #pragma unroll
                for (int y = 0; y < NSPLIT; y++) {
                    float4 t = *reinterpret_cast<const float4*>(
                        ZtRp + ((size_t)y * Z_DIM + kn) * P_DIM + p0);
                    zk[0] += t.x; zk[1] += t.y; zk[2] += t.z; zk[3] += t.w;
                }
            }
        }
        float cc[PPT];
        #pragma unroll
        for (int i = 0; i < PPT; i++) cc[i] = um[i] * esv[i];   // wk += cc*scale later

        // ---- poll all 196 wave partials (64 lanes x 3-4 slots, parallel loads) ----
        const unsigned long long* sb = part + (size_t)s * SLOT_STRIDE;
        unsigned long long v0 = 0, v1 = 0, v2 = 0;
        unsigned long long v3 = need3 ? 0ULL : (1ULL << 32);    // pre-mark unused as ready
        for (int it = 0; it < SPIN_MAX; it++) {
            if (!(unsigned)(v0 >> 32))
                v0 = __hip_atomic_load(sb + lane,       __ATOMIC_RELAXED, __HIP_MEMORY_SCOPE_AGENT);
            if (!(unsigned)(v1 >> 32))
                v1 = __hip_atomic_load(sb + 64 + lane,  __ATOMIC_RELAXED, __HIP_MEMORY_SCOPE_AGENT);
            if (!(unsigned)(v2 >> 32))
                v2 = __hip_atomic_load(sb + 128 + lane, __ATOMIC_RELAXED, __HIP_MEMORY_SCOPE_AGENT);
            if (!(unsigned)(v3 >> 32))
                v3 = __hip_atomic_load(sb + 192 + lane, __ATOMIC_RELAXED, __HIP_MEMORY_SCOPE_AGENT);
            if ((unsigned)(v0 >> 32) && (unsigned)(v1 >> 32) &&
                (unsigned)(v2 >> 32) && (unsigned)(v3 >> 32)) break;
        }
        // two-pass merge. Fake/ready-marked slots carry (m=0, e~0): m=0 can only
        // inflate M (harmless: scale is M-shift invariant; real maxima >= log(1/P)),
        // and e~0 contributes nothing to the sum.
        float m0 = __uint_as_float((unsigned)v0), e0 = __uint_as_float((unsigned)(v0 >> 32));
        float m1 = __uint_as_float((unsigned)v1), e1 = __uint_as_float((unsigned)(v1 >> 32));
        float m2 = __uint_as_float((unsigned)v2), e2 = __uint_as_float((unsigned)(v2 >> 32));
        float m3 = __uint_as_float((unsigned)v3), e3 = __uint_as_float((unsigned)(v3 >> 32));
        float mm = fmaxf(fmaxf(m0, m1), fmaxf(m2, m3));
        #pragma unroll
        for (int off = 32; off > 0; off >>= 1) mm = fmaxf(mm, __shfl_xor(mm, off));
        const float M = mm;                        // global max, all lanes
        float ss = e0 * __expf(m0 - M) + e1 * __expf(m1 - M)
                 + e2 * __expf(m2 - M) + e3 * __expf(m3 - M);
        #pragma unroll
        for (int off = 32; off > 0; off >>= 1) ss += __shfl_xor(ss, off);
        const float scale = __expf(Mw - M) / ss;   // alpha_i = esv[i] * scale

        // ---- finalize step (k,l) ----
        if (valid) {
            float a[PPT];
            #pragma unroll
            for (int i = 0; i < PPT; i++) {
                a[i]  = esv[i] * scale;
                wk[i] = fmaf(cc[i], scale, wkl[i]);
            }
            float4 sv = make_float4(a[0], a[1], a[2], a[3]);
            *reinterpret_cast<float4*>(out_al + io) = sv;
        }
        if (tid == 0 && bid == 0) out_vw[l * Z_DIM + k] = u_var;

        if (l == L_DIM - 1) {
            #pragma unroll
            for (int j = 0; j < Z_DIM; j++)
                if (j == k)
                    #pragma unroll
                    for (int i = 0; i < PPT; i++) W[j][i] = wk[i];
        }
        #pragma unroll
        for (int i = 0; i < PPT; i++) { mw_c[i] = mw_n[i]; al_c[i] = al_n[i]; }
        k = kn; l = ln;
    }
}

extern "C" void kernel_launch(void* const* d_in, const int* in_sizes, int n_in,
                              void* d_out, int out_size, void* d_ws, size_t ws_size,
                              hipStream_t stream) {
    (void)in_sizes; (void)n_in; (void)out_size; (void)ws_size;
    const float* data   = (const float*)d_in[0];
    const float* mean_z = (const float*)d_in[1];
    const float* var_z  = (const float*)d_in[2];
    const float* mw0    = (const float*)d_in[3];
    // d_in[4] var_w: unused (fully overwritten in output)
    const float* al0    = (const float*)d_in[5];
    const float* tau0   = (const float*)d_in[6];
    const float* pi     = (const float*)d_in[7];
    const float* taup   = (const float*)d_in[8];
    float* out = (float*)d_out;
    float* ws  = (float*)d_ws;

    // one fused precompute launch: ZtRp chunks + W0 + zz + partial-slot zeroing
    precompute_big<<<dim3(NBP, NSPLIT + 1), NTP, 0, stream>>>(data, mean_z, var_z,
                                                              mw0, al0, ws);
    steps_fused<<<NBLK, NT1, 0, stream>>>(mw0, al0, pi, tau0, taup, ws, out);
}

// Round 5
// 468.715 us; speedup vs baseline: 1.0274x; 1.0274x over previous
//
#include <hip/hip_runtime.h>
#include <math.h>

#define N_DIM 1000
#define P_DIM 50000
#define Z_DIM 10
#define L_DIM 5
#define NSTEP 50

// precompute grid
#define NTP 256
#define NBP 196          // ceil(50000/256)
#define NSPLIT 4
#define NCHUNK 250       // N_DIM / NSPLIT

// persistent step kernel: 25 blocks x 256 thr x 8 p/thread = 51200 >= 50000.
// Sync per step: each of the 100 waves publishes its own packed (Mw,Ew) partial
// (no pre-barriers); ONLY wave 0 of each block polls the 100 slots (<=2/lane),
// merges, broadcasts (M,ss) via LDS + one __syncthreads. Minimizes both publish
// latency (r3 flaw) and poll fan-in/contention (r4 flaw).
#define NT1 256
#define PPT 8
#define PBLK (NT1 * PPT)     // 2048 p per block
#define NBLK 25
#define NWAVES (NBLK * 4)    // 100
#define SLOT_STRIDE 128      // u64 slots reserved per step (100 used)
#define NEG_BIG (-3.0e38f)
#define SPIN_MAX 32768       // bounded spin: sync failure -> wrong result, not a hang

// ---- workspace layout (floats) ----
constexpr size_t ZP       = (size_t)Z_DIM * P_DIM;            // 500000
constexpr size_t OFF_PART = 0;                                // u64[NSTEP*SLOT_STRIDE]
constexpr size_t PART_F   = (size_t)NSTEP * SLOT_STRIDE * 2;  // in floats (12800)
constexpr size_t OFF_ZTRP = PART_F;                           // [NSPLIT][Z][P] (no atomics)
constexpr size_t OFF_W    = OFF_ZTRP + (size_t)NSPLIT * ZP;   // [Z][P] W0
constexpr size_t OFF_ZZ   = OFF_W + ZP;                       // [Z*Z], reserve 128

// ---- output layout (floats) ----
constexpr size_t OUT_MW = 0;
constexpr size_t OUT_VW = (size_t)L_DIM * Z_DIM * P_DIM;      // 2,500,000
constexpr size_t OUT_AL = OUT_VW + (size_t)L_DIM * Z_DIM;     // 2,500,050

// Fused precompute (one launch, grid y = NSPLIT+1 rows):
//  rows 0..NSPLIT-1 : ZtRp[y][z][p] = chunk-y of mean_z^T @ data (plain stores)
//                     + W0[z][p] on row 0
//  row  NSPLIT      : bx < 100       -> zz[bx] = mean_z^T mean_z + N*var_z
//                     bx in [100,196)-> zero the NSTEP*SLOT_STRIDE partial slots
__global__ __launch_bounds__(NTP) void precompute_big(const float* __restrict__ data,
                                                      const float* __restrict__ mean_z,
                                                      const float* __restrict__ var_z,
                                                      const float* __restrict__ mw0,
                                                      const float* __restrict__ al0,
                                                      float* __restrict__ ws) {
    if (blockIdx.y == NSPLIT) {
        int bx = blockIdx.x;
        if (bx < Z_DIM * Z_DIM) {
            float* zz = ws + OFF_ZZ;
            int i = bx / Z_DIM, j = bx % Z_DIM;
            float s = 0.f;
            for (int n = threadIdx.x; n < N_DIM; n += NTP)
                s += mean_z[n * Z_DIM + i] * mean_z[n * Z_DIM + j];
            #pragma unroll
            for (int off = 32; off > 0; off >>= 1) s += __shfl_xor(s, off);
            __shared__ float ls[4];
            if ((threadIdx.x & 63) == 0) ls[threadIdx.x >> 6] = s;
            __syncthreads();
            if (threadIdx.x == 0) {
                float t = ls[0] + ls[1] + ls[2] + ls[3];
                zz[bx] = t + (float)N_DIM * var_z[bx];
            }
        } else {
            // zero partial slots (ws is poisoned 0xAA; poisoned slots look "ready")
            unsigned long long* part = reinterpret_cast<unsigned long long*>(ws + OFF_PART);
            int idx = (bx - Z_DIM * Z_DIM) * NTP + threadIdx.x;
            if (idx < NSTEP * SLOT_STRIDE) part[idx] = 0ULL;
        }
        return;
    }

    float* ZtRp = ws + OFF_ZTRP + (size_t)blockIdx.y * ZP;
    float* W    = ws + OFF_W;
    __shared__ float mzs[NCHUNK * Z_DIM];   // 10 KB
    int n0 = blockIdx.y * NCHUNK;
    for (int i = threadIdx.x; i < NCHUNK * Z_DIM; i += NTP)
        mzs[i] = mean_z[n0 * Z_DIM + i];
    __syncthreads();
    int p = blockIdx.x * NTP + threadIdx.x;
    if (p >= P_DIM) return;

    float acc[Z_DIM];
    #pragma unroll
    for (int z = 0; z < Z_DIM; z++) acc[z] = 0.f;
    for (int r = 0; r < NCHUNK; r++) {
        float d = data[(size_t)(n0 + r) * P_DIM + p];
        #pragma unroll
        for (int z = 0; z < Z_DIM; z++) acc[z] = fmaf(mzs[r * Z_DIM + z], d, acc[z]);
    }
    #pragma unroll
    for (int z = 0; z < Z_DIM; z++) ZtRp[(size_t)z * P_DIM + p] = acc[z];

    if (blockIdx.y == 0) {
        #pragma unroll
        for (int z = 0; z < Z_DIM; z++) {
            float w = 0.f;
            #pragma unroll
            for (int l = 0; l < L_DIM; l++) {
                size_t io = ((size_t)l * Z_DIM + z) * P_DIM + p;
                w = fmaf(mw0[io], al0[io], w);
            }
            W[(size_t)z * P_DIM + p] = w;
        }
    }
}

// All 50 (k,l) steps in one persistent kernel. Per-p state in registers throughout.
__global__ __launch_bounds__(NT1) void steps_fused(const float* __restrict__ mw0,
                                                   const float* __restrict__ al0,
                                                   const float* __restrict__ pi,
                                                   const float* __restrict__ tau0,
                                                   const float* __restrict__ taup,
                                                   float* __restrict__ ws,
                                                   float* __restrict__ out) {
    const float* ZtRp = ws + OFF_ZTRP;
    const float* Wg   = ws + OFF_W;
    const float* zz   = ws + OFF_ZZ;
    unsigned long long* part = reinterpret_cast<unsigned long long*>(ws + OFF_PART);
    float* out_mw = out + OUT_MW;
    float* out_vw = out + OUT_VW;
    float* out_al = out + OUT_AL;

    __shared__ float bro[2][2];   // (M, ss) double-buffered by s&1

    const int tid  = threadIdx.x;
    const int bid  = blockIdx.x;
    const int lane = tid & 63;
    const int wid  = tid >> 6;
    const int gw   = bid * 4 + wid;              // global wave id, 0..99
    const int p0   = bid * PBLK + tid * PPT;     // 8 consecutive p; P%8==0 -> all-or-none
    const bool valid = p0 < P_DIM;
    const float tau = taup[0];
    // unused 2nd poll slot sentinel: ready flag set, zero contribution
    const unsigned long long READY0 =
        ((unsigned long long)1u << 32) | (unsigned long long)__float_as_uint(NEG_BIG);

    // ---- per-p register state (all indices compile-time after unroll) ----
    float W[Z_DIM][PPT];
    #pragma unroll
    for (int z = 0; z < Z_DIM; z++)
        #pragma unroll
        for (int i = 0; i < PPT; i++) W[z][i] = 0.f;
    float mw_c[PPT], al_c[PPT], lpi[PPT], zk[PPT];
    #pragma unroll
    for (int i = 0; i < PPT; i++) { mw_c[i] = 0.f; al_c[i] = 0.f; lpi[i] = 0.f; zk[i] = 0.f; }
    if (valid) {
        #pragma unroll
        for (int z = 0; z < Z_DIM; z++) {
            float4 a = *reinterpret_cast<const float4*>(Wg + (size_t)z * P_DIM + p0);
            float4 b = *reinterpret_cast<const float4*>(Wg + (size_t)z * P_DIM + p0 + 4);
            W[z][0] = a.x; W[z][1] = a.y; W[z][2] = a.z; W[z][3] = a.w;
            W[z][4] = b.x; W[z][5] = b.y; W[z][6] = b.z; W[z][7] = b.w;
        }
        float4 ma = *reinterpret_cast<const float4*>(mw0 + p0);        // step 0: k=0,l=0
        float4 mb = *reinterpret_cast<const float4*>(mw0 + p0 + 4);
        float4 aa = *reinterpret_cast<const float4*>(al0 + p0);
        float4 ab = *reinterpret_cast<const float4*>(al0 + p0 + 4);
        mw_c[0]=ma.x; mw_c[1]=ma.y; mw_c[2]=ma.z; mw_c[3]=ma.w;
        mw_c[4]=mb.x; mw_c[5]=mb.y; mw_c[6]=mb.z; mw_c[7]=mb.w;
        al_c[0]=aa.x; al_c[1]=aa.y; al_c[2]=aa.z; al_c[3]=aa.w;
        al_c[4]=ab.x; al_c[5]=ab.y; al_c[6]=ab.z; al_c[7]=ab.w;
        #pragma unroll
        for (int i = 0; i < PPT; i++) lpi[i] = __logf(pi[p0 + i]);
        #pragma unroll
        for (int y = 0; y < NSPLIT; y++) {                              // Zt[k=0]
            const float* src = ZtRp + ((size_t)y * Z_DIM + 0) * P_DIM + p0;
            float4 a = *reinterpret_cast<const float4*>(src);
            float4 b = *reinterpret_cast<const float4*>(src + 4);
            zk[0]+=a.x; zk[1]+=a.y; zk[2]+=a.z; zk[3]+=a.w;
            zk[4]+=b.x; zk[5]+=b.y; zk[6]+=b.z; zk[7]+=b.w;
        }
    }

    float wk[PPT], r[PPT];
    #pragma unroll
    for (int i = 0; i < PPT; i++) { wk[i] = 0.f; r[i] = 0.f; }
    int k = 0, l = 0;

    #pragma unroll 1
    for (int s = 0; s < NSTEP; s++) {
        // ---- per-step uniform scalars ----
        const float Ezz   = zz[k * Z_DIM + k];
        const float t0v   = tau0[l * Z_DIM + k];
        const float u_var = 1.f / (tau * Ezz + t0v);
        const float s2    = 1.f / (Ezz * tau);
        const float s0inv = 1.f / t0v;
        const float cq    = 0.5f * (tau / Ezz) * (s0inv / (s2 + s0inv));

        if (l == 0) {
            // fresh factor k: r = Zt[k] - sum_{j!=k} zz[k,j]*W[j]; wk = W[k]
            #pragma unroll
            for (int i = 0; i < PPT; i++) r[i] = zk[i];
            #pragma unroll
            for (int j = 0; j < Z_DIM; j++) {
                float c = (j == k) ? 0.f : zz[k * Z_DIM + j];     // uniform select
                #pragma unroll
                for (int i = 0; i < PPT; i++) r[i] = fmaf(-c, W[j][i], r[i]);
                if (j == k)
                    #pragma unroll
                    for (int i = 0; i < PPT; i++) wk[i] = W[j][i];
            }
        }

        // ---- minimal pre-publish path: logits -> wave reduce -> publish ----
        float wkl[PPT], E[PPT], lgt[PPT];
        #pragma unroll
        for (int i = 0; i < PPT; i++) { wkl[i] = 0.f; E[i] = 0.f; lgt[i] = NEG_BIG; }
        if (valid) {
            #pragma unroll
            for (int i = 0; i < PPT; i++) {
                wkl[i] = wk[i] - mw_c[i] * al_c[i];
                E[i]   = fmaf(-Ezz, wkl[i], r[i]);
                lgt[i] = fmaf(cq * E[i], E[i], lpi[i]);
            }
        }
        float m4 = lgt[0];
        #pragma unroll
        for (int i = 1; i < PPT; i++) m4 = fmaxf(m4, lgt[i]);
        #pragma unroll
        for (int off = 32; off > 0; off >>= 1) m4 = fmaxf(m4, __shfl_xor(m4, off));
        const float Mw = m4;                       // wave max, all lanes
        float esv[PPT];
        #pragma unroll
        for (int i = 0; i < PPT; i++) esv[i] = __expf(lgt[i] - Mw);
        float s4 = 0.f;
        #pragma unroll
        for (int i = 0; i < PPT; i++) s4 += esv[i];
        #pragma unroll
        for (int off = 32; off > 0; off >>= 1) s4 += __shfl_xor(s4, off);
        if (lane == 0) {
            // fully-valid wave: Ew>=1; fully-invalid wave: Mw=NEG_BIG, esv=1 -> Ew=512
            // and Ew*exp(Mw-M)=0 in the merge. Either way hi word != 0 (ready).
            unsigned long long v = ((unsigned long long)__float_as_uint(s4) << 32)
                                 | (unsigned long long)__float_as_uint(Mw);
            __hip_atomic_store(&part[(size_t)s * SLOT_STRIDE + gw], v, __ATOMIC_RELAXED,
                               __HIP_MEMORY_SCOPE_AGENT);
        }

        // ---- poll window: deferred um/store + next-step prefetch ----
        const size_t io = ((size_t)l * Z_DIM + k) * P_DIM + p0;
        float cc[PPT];
        #pragma unroll
        for (int i = 0; i < PPT; i++) cc[i] = 0.f;
        if (valid) {
            float um[PPT];
            #pragma unroll
            for (int i = 0; i < PPT; i++) um[i] = tau * u_var * E[i];
            *reinterpret_cast<float4*>(out_mw + io)     = make_float4(um[0],um[1],um[2],um[3]);
            *reinterpret_cast<float4*>(out_mw + io + 4) = make_float4(um[4],um[5],um[6],um[7]);
            #pragma unroll
            for (int i = 0; i < PPT; i++) cc[i] = um[i] * esv[i];   // wk += cc*scale later
        }
        int kn = k, ln = l + 1;
        if (ln == L_DIM) { ln = 0; kn++; }
        float mw_n[PPT], al_n[PPT];
        #pragma unroll
        for (int i = 0; i < PPT; i++) { mw_n[i] = 0.f; al_n[i] = 0.f; }
        if (valid && s + 1 < NSTEP) {
            size_t ion = ((size_t)ln * Z_DIM + kn) * P_DIM + p0;
            float4 ma = *reinterpret_cast<const float4*>(mw0 + ion);
            float4 mb = *reinterpret_cast<const float4*>(mw0 + ion + 4);
            float4 aa = *reinterpret_cast<const float4*>(al0 + ion);
            float4 ab = *reinterpret_cast<const float4*>(al0 + ion + 4);
            mw_n[0]=ma.x; mw_n[1]=ma.y; mw_n[2]=ma.z; mw_n[3]=ma.w;
            mw_n[4]=mb.x; mw_n[5]=mb.y; mw_n[6]=mb.z; mw_n[7]=mb.w;
            al_n[0]=aa.x; al_n[1]=aa.y; al_n[2]=aa.z; al_n[3]=aa.w;
            al_n[4]=ab.x; al_n[5]=ab.y; al_n[6]=ab.z; al_n[7]=ab.w;
            if (ln == 0) {                        // next factor: lpi + Zt[kn] early
                #pragma unroll
                for (int i = 0; i < PPT; i++) lpi[i] = __logf(pi[(size_t)kn * P_DIM + p0 + i]);
                #pragma unroll
                for (int i = 0; i < PPT; i++) zk[i] = 0.f;
                #pragma unroll
                for (int y = 0; y < NSPLIT; y++) {
                    const float* src = ZtRp + ((size_t)y * Z_DIM + kn) * P_DIM + p0;
                    float4 a = *reinterpret_cast<const float4*>(src);
                    float4 b = *reinterpret_cast<const float4*>(src + 4);
                    zk[0]+=a.x; zk[1]+=a.y; zk[2]+=a.z; zk[3]+=a.w;
                    zk[4]+=b.x; zk[5]+=b.y; zk[6]+=b.z; zk[7]+=b.w;
                }
            }
        }

        // ---- wave 0 only: poll the 100 slots (<=2/lane), merge, broadcast ----
        if (wid == 0) {
            const unsigned long long* sb = part + (size_t)s * SLOT_STRIDE;
            unsigned long long v0 = 0;
            unsigned long long v1 = (lane < NWAVES - 64) ? 0ULL : READY0;
            for (int it = 0; it < SPIN_MAX; it++) {
                if (!(unsigned)(v0 >> 32))
                    v0 = __hip_atomic_load(sb + lane,      __ATOMIC_RELAXED, __HIP_MEMORY_SCOPE_AGENT);
                if (!(unsigned)(v1 >> 32))
                    v1 = __hip_atomic_load(sb + 64 + lane, __ATOMIC_RELAXED, __HIP_MEMORY_SCOPE_AGENT);
                if ((unsigned)(v0 >> 32) && (unsigned)(v1 >> 32)) break;
            }
            float m0 = __uint_as_float((unsigned)v0), e0 = __uint_as_float((unsigned)(v0 >> 32));
            float m1 = __uint_as_float((unsigned)v1), e1 = __uint_as_float((unsigned)(v1 >> 32));
            float mm = fmaxf(m0, m1);
            #pragma unroll
            for (int off = 32; off > 0; off >>= 1) mm = fmaxf(mm, __shfl_xor(mm, off));
            float ss = e0 * __expf(m0 - mm) + e1 * __expf(m1 - mm);
            #pragma unroll
            for (int off = 32; off > 0; off >>= 1) ss += __shfl_xor(ss, off);
            if (lane == 0) { bro[s & 1][0] = mm; bro[s & 1][1] = ss; }
        }
        __syncthreads();
        const float M     = bro[s & 1][0];
        const float scale = __expf(Mw - M) / bro[s & 1][1];   // alpha_i = esv[i]*scale

        // ---- finalize step (k,l) ----
        if (valid) {
            float a[PPT];
            #pragma unroll
            for (int i = 0; i < PPT; i++) {
                a[i]  = esv[i] * scale;
                wk[i] = fmaf(cc[i], scale, wkl[i]);
            }
            *reinterpret_cast<float4*>(out_al + io)     = make_float4(a[0],a[1],a[2],a[3]);
            *reinterpret_cast<float4*>(out_al + io + 4) = make_float4(a[4],a[5],a[6],a[7]);
        }
        if (tid == 0 && bid == 0) out_vw[l * Z_DIM + k] = u_var;

        if (l == L_DIM - 1) {
            #pragma unroll
            for (int j = 0; j < Z_DIM; j++)
                if (j == k)
                    #pragma unroll
                    for (int i = 0; i < PPT; i++) W[j][i] = wk[i];
        }
        #pragma unroll
        for (int i = 0; i < PPT; i++) { mw_c[i] = mw_n[i]; al_c[i] = al_n[i]; }
        k = kn; l = ln;
    }
}

extern "C" void kernel_launch(void* const* d_in, const int* in_sizes, int n_in,
                              void* d_out, int out_size, void* d_ws, size_t ws_size,
                              hipStream_t stream) {
    (void)in_sizes; (void)n_in; (void)out_size; (void)ws_size;
    const float* data   = (const float*)d_in[0];
    const float* mean_z = (const float*)d_in[1];
    const float* var_z  = (const float*)d_in[2];
    const float* mw0    = (const float*)d_in[3];
    // d_in[4] var_w: unused (fully overwritten in output)
    const float* al0    = (const float*)d_in[5];
    const float* tau0   = (const float*)d_in[6];
    const float* pi     = (const float*)d_in[7];
    const float* taup   = (const float*)d_in[8];
    float* out = (float*)d_out;
    float* ws  = (float*)d_ws;

    // one fused precompute launch: ZtRp chunks + W0 + zz + partial-slot zeroing
    precompute_big<<<dim3(NBP, NSPLIT + 1), NTP, 0, stream>>>(data, mean_z, var_z,
                                                              mw0, al0, ws);
    steps_fused<<<NBLK, NT1, 0, stream>>>(mw0, al0, pi, tau0, taup, ws, out);
}